// Round 8
// baseline (4995.996 us; speedup 1.0000x reference)
//
#include <hip/hip_runtime.h>
#include <hip/hip_bf16.h>
#include <math.h>

typedef __hip_bfloat16 bf16;
typedef short bf16x8 __attribute__((ext_vector_type(8)));
typedef float f32x4 __attribute__((ext_vector_type(4)));

static constexpr int HWPX = 16384;   // 128*128

__device__ inline float sigmoidf_(float x) { return 1.0f / (1.0f + expf(-x)); }
__device__ inline float bflo(unsigned u) { return __uint_as_float(u << 16); }
__device__ inline float bfhi(unsigned u) { return __uint_as_float(u & 0xffff0000u); }
__device__ inline int swz(int x) { return (x ^ (x >> 2)) & 3; }

// async global->LDS, 16B per lane; lds base wave-uniform (lane i -> +i*16)
__device__ inline void gll16(const bf16* g, short* l) {
    __builtin_amdgcn_global_load_lds(
        (const __attribute__((address_space(1))) void*)g,
        (__attribute__((address_space(3))) void*)l, 16, 0, 0);
}

// device-scope grid barrier (monotonic counter; all blocks must be resident)
__device__ inline void gridbar(unsigned* bar, unsigned target) {
    __syncthreads();
    if (threadIdx.x == 0) {
        __threadfence();
        __hip_atomic_fetch_add(bar, 1u, __ATOMIC_ACQ_REL, __HIP_MEMORY_SCOPE_AGENT);
        while (__hip_atomic_load(bar, __ATOMIC_ACQUIRE, __HIP_MEMORY_SCOPE_AGENT) < target) {
            __builtin_amdgcn_s_sleep(8);
        }
    }
    __syncthreads();
}

// ---------------- prep: LSTM weights -> bf16 (wih0 padded 70->72) -----------
__global__ __launch_bounds__(256) void prep_lstm_k(
    const float* __restrict__ wih0, const float* __restrict__ whh0,
    const float* __restrict__ wihr, const float* __restrict__ whhr,
    bf16* __restrict__ d0, bf16* __restrict__ d1,
    bf16* __restrict__ d2, bf16* __restrict__ d3)
{
    const size_t nA = 2048ull * 72, nB = 2048ull * 512;
    const size_t nC = 5ull * 2048 * 576, nD = 5ull * 2048 * 512;
    for (size_t i = blockIdx.x * 256ull + threadIdx.x; i < nA + nB + nC + nD;
         i += (size_t)gridDim.x * 256) {
        if (i < nA) {
            int c = (int)(i % 72), r = (int)(i / 72);
            d0[i] = __float2bfloat16(c < 70 ? wih0[(size_t)r * 70 + c] : 0.f);
        } else if (i < nA + nB) {
            size_t k = i - nA; d1[k] = __float2bfloat16(whh0[k]);
        } else if (i < nA + nB + nC) {
            size_t k = i - nA - nB; d2[k] = __float2bfloat16(wihr[k]);
        } else {
            size_t k = i - nA - nB - nC; d3[k] = __float2bfloat16(whhr[k]);
        }
    }
}

// ---------------- prep: conv weights, both cams -----------------------------
struct ConvW {
    const float* src[8];
    bf16* dst[8];
};

__global__ __launch_bounds__(256) void prep_conv_k(ConvW a)
{
    const int sizes[4] = {3072, 18432, 73728, 18432};
    const int cins[4] = {3, 32, 64, 128};
    const int couts[4] = {32, 64, 128, 16};
    int total = 2 * 113664;
    for (int idx = blockIdx.x * 256 + threadIdx.x; idx < total; idx += gridDim.x * 256) {
        int i = idx, cam = 0;
        if (i >= 113664) { cam = 1; i -= 113664; }
        int layer = 0;
        while (layer < 3 && i >= sizes[layer]) { i -= sizes[layer]; ++layer; }
        const float* w = a.src[cam * 4 + layer];
        bf16* d = a.dst[cam * 4 + layer];
        if (layer == 0) {
            // [3ky][32co][32k], k = kx*8 + c
            int k = i & 31, co = (i >> 5) & 31, ky = i >> 10;
            int kx = k >> 3, c = k & 7;
            float v = (kx < 3 && c < 3) ? w[((co * 3 + c) * 3 + ky) * 3 + kx] : 0.f;
            d[i] = __float2bfloat16(v);
        } else {
            // dst [tap][kc][q][co][8]
            int CIN = cins[layer], COUT = couts[layer], KC = CIN / 32;
            int e = i & 7;
            int t2 = i >> 3;
            int co = t2 % COUT;
            int t3 = t2 / COUT;
            int q = t3 & 3;
            int t4 = t3 >> 2;
            int kc = t4 % KC;
            int tap = t4 / KC;
            d[i] = __float2bfloat16(w[((size_t)(co * CIN + kc * 32 + q * 8 + e)) * 9 + tap]);
        }
    }
}

// ---------------- conv L0: fp32 NCHW in, NHWC-32 out, cam-folded ------------
__global__ __launch_bounds__(256) void conv0_nhwc(
    const float* __restrict__ srcm, const float* __restrict__ srcs,
    const bf16* __restrict__ w0m, const bf16* __restrict__ w0s,
    const float* __restrict__ bm, const float* __restrict__ bs,
    bf16* __restrict__ out, int c0)
{
    const int y = blockIdx.x;
    const int cam = blockIdx.y;
    const int img = blockIdx.z;
    const int ci_ = cam * gridDim.z + img;
    const float* inImg = (cam ? srcs : srcm) + (size_t)(c0 + img) * 3 * HWPX;
    const bf16* wT0 = cam ? w0s : w0m;
    const float* bias = cam ? bs : bm;
    const int tid = threadIdx.x;
    const int wave = tid >> 6, lane = tid & 63;
    const int wm = wave & 1, wn = wave >> 1;
    const int q = lane >> 4, n16 = lane & 15;

    __shared__ short smem[3 * 130 * 16];

    for (int d = tid; d < 3 * 130; d += 256) {
        int x = d % 130, r = d / 130;
        int yy = y + r - 1, xx = x - 1;
        bf16 v8[8];
#pragma unroll
        for (int c = 0; c < 8; ++c) v8[c] = __float2bfloat16(0.f);
        if ((unsigned)yy < 128u && (unsigned)xx < 128u) {
            int o = yy * 128 + xx;
            v8[0] = __float2bfloat16(inImg[o]);
            v8[1] = __float2bfloat16(inImg[HWPX + o]);
            v8[2] = __float2bfloat16(inImg[2 * HWPX + o]);
        }
        *(bf16x8*)(void*)&smem[(r * 130 + x) * 16] = *(bf16x8*)(void*)v8;
        *(bf16x8*)(void*)&smem[(r * 130 + x) * 16 + 8] = (bf16x8)0;
    }
    __syncthreads();

    f32x4 acc[4];
#pragma unroll
    for (int nt = 0; nt < 4; ++nt) acc[nt] = f32x4{0.f, 0.f, 0.f, 0.f};

    const int co = wm * 16 + n16;
#pragma unroll
    for (int ky = 0; ky < 3; ++ky) {
        bf16x8 aF = *(const bf16x8*)(const void*)(wT0 + ((size_t)(ky * 32 + co) * 32) + q * 8);
#pragma unroll
        for (int nt = 0; nt < 4; ++nt) {
            int x = (wn * 4 + nt) * 16 + n16;
            int off = (q < 3) ? (ky * 130 + x + q) * 16 : (ky * 130 + x) * 16 + 8;
            bf16x8 bF = *(const bf16x8*)(const void*)&smem[off];
            acc[nt] = __builtin_amdgcn_mfma_f32_16x16x32_bf16(aF, bF, acc[nt], 0, 0, 0);
        }
    }

    int co0 = wm * 16 + q * 4;
#pragma unroll
    for (int nt = 0; nt < 4; ++nt) {
        int x = (wn * 4 + nt) * 16 + n16;
        bf16 tmp[4];
#pragma unroll
        for (int r = 0; r < 4; ++r) {
            float v = acc[nt][r] + bias[co0 + r];
            tmp[r] = __float2bfloat16(v > 0.f ? v : 0.f);
        }
        *reinterpret_cast<uint2*>(out + ((size_t)ci_ * HWPX + y * 128 + x) * 32 + co0)
            = *reinterpret_cast<uint2*>(tmp);
    }
}

// ---------------- mid convs: 2 rows x 64px per block, gll dbuf --------------
template <int CIN, int COUT>
__global__ __launch_bounds__(256, 4) void conv2r(
    const bf16* __restrict__ in, const bf16* __restrict__ wTm,
    const bf16* __restrict__ wTs, const float* __restrict__ bm,
    const float* __restrict__ bs, bf16* __restrict__ out,
    const char* __restrict__ zpage)
{
    constexpr int KC = CIN / 32;
    constexpr int NB = (KC > 1) ? 2 : 1;
    constexpr int MW = COUT / 32;       // co tiles per wave (2 co-halves)
    constexpr int SLOTS = 4 * 264;      // 4 rows x 66 x x 4 granules

    const int y0 = (blockIdx.x >> 1) * 2;
    const int x0 = (blockIdx.x & 1) * 64;
    const int cam = blockIdx.y;
    const int img = blockIdx.z;
    const int ci_ = cam * gridDim.z + img;
    const bf16* wT = cam ? wTs : wTm;
    const float* bias = cam ? bs : bm;
    const int tid = threadIdx.x;
    const int wave = tid >> 6, lane = tid & 63;
    const int wrow = wave >> 1, wm = wave & 1;
    const int q = lane >> 4, n16 = lane & 15;

    __shared__ short smem[NB][SLOTS * 8];
    const bf16* inImg = in + (size_t)ci_ * HWPX * CIN;

    const bf16* sptr[5];
#pragma unroll
    for (int it = 0; it < 5; ++it) {
        int s = it * 256 + tid;
        int r = s / 264, s2 = s - r * 264;
        int sx = s2 >> 2;
        int g = (s2 & 3) ^ swz(sx);
        int yy = y0 + r - 1, xx = x0 + sx - 1;
        bool ok = (s < SLOTS) && ((unsigned)yy < 128u) && ((unsigned)xx < 128u);
        sptr[it] = ok ? inImg + ((size_t)yy * 128 + xx) * CIN + g * 8
                      : (const bf16*)(zpage + (tid & 255) * 16);
    }
    auto stage = [&](int kc, int buf) {
#pragma unroll
        for (int it = 0; it < 5; ++it) {
            if (it * 256 + tid < SLOTS)
                gll16(sptr[it] + kc * 32, &smem[buf][it * 2048 + wave * 512]);
        }
    };

    f32x4 acc[MW][4];
#pragma unroll
    for (int mt = 0; mt < MW; ++mt)
#pragma unroll
        for (int nt = 0; nt < 4; ++nt) acc[mt][nt] = f32x4{0.f, 0.f, 0.f, 0.f};

    stage(0, 0);
    for (int kc = 0; kc < KC; ++kc) {
        __syncthreads();
        if (kc + 1 < KC) stage(kc + 1, (kc + 1) % NB);
        const short* sb = smem[kc % NB];
#pragma unroll
        for (int ky = 0; ky < 3; ++ky) {
#pragma unroll
            for (int kx = 0; kx < 3; ++kx) {
                bf16x8 aF[MW];
#pragma unroll
                for (int mt = 0; mt < MW; ++mt) {
                    int co = (wm * MW + mt) * 16 + n16;
                    aF[mt] = *(const bf16x8*)(const void*)(wT +
                        ((((size_t)(ky * 3 + kx) * KC + kc) * 4 + q) * COUT + co) * 8);
                }
#pragma unroll
                for (int nt = 0; nt < 4; ++nt) {
                    int xt = nt * 16 + n16 + kx;           // 0..65
                    int slot = (wrow + ky) * 264 + xt * 4 + (q ^ swz(xt));
                    bf16x8 bF = *(const bf16x8*)(const void*)&sb[slot * 8];
#pragma unroll
                    for (int mt = 0; mt < MW; ++mt)
                        acc[mt][nt] = __builtin_amdgcn_mfma_f32_16x16x32_bf16(
                            aF[mt], bF, acc[mt][nt], 0, 0, 0);
                }
            }
        }
    }

    const int y = y0 + wrow;
#pragma unroll
    for (int mt = 0; mt < MW; ++mt) {
        int co0 = (wm * MW + mt) * 16 + q * 4;
#pragma unroll
        for (int nt = 0; nt < 4; ++nt) {
            int x = x0 + nt * 16 + n16;
            bf16 tmp[4];
#pragma unroll
            for (int r = 0; r < 4; ++r) {
                float v = acc[mt][nt][r] + bias[co0 + r];
                tmp[r] = __float2bfloat16(v > 0.f ? v : 0.f);
            }
            *reinterpret_cast<uint2*>(out + ((size_t)ci_ * HWPX + y * 128 + x) * COUT + co0)
                = *reinterpret_cast<uint2*>(tmp);
        }
    }
}

// ---------------- conv4 (128->16): half-row x-split + softmax partials ------
__global__ __launch_bounds__(256, 6) void conv4_xs(
    const bf16* __restrict__ in, const bf16* __restrict__ wTm,
    const bf16* __restrict__ wTs, const float* __restrict__ bm,
    const float* __restrict__ bs,
    float* __restrict__ partial,   // [gimg][16][256] x {M,S,SX,-}
    const char* __restrict__ zpage, int c0)
{
    constexpr int CIN = 128, COUT = 16, KC = 4;
    constexpr int SLOTS = 3 * 66 * 4;
    const int y = blockIdx.x >> 1;
    const int xh = blockIdx.x & 1;
    const int x0 = xh * 64;
    const int cam = blockIdx.y;
    const int img = blockIdx.z;
    const int ci_ = cam * gridDim.z + img;
    const int gimg = cam * 40 + c0 + img;
    const bf16* wT = cam ? wTs : wTm;
    const float* bias = cam ? bs : bm;
    const int tid = threadIdx.x;
    const int wave = tid >> 6, lane = tid & 63;
    const int q = lane >> 4, n16 = lane & 15;

    __shared__ short smem[2][SLOTS * 8];
    __shared__ float sred[3][4][16];
    const bf16* inImg = in + (size_t)ci_ * HWPX * CIN;

    const bf16* sptr[4];
#pragma unroll
    for (int it = 0; it < 4; ++it) {
        int s = it * 256 + tid;
        int r = s / 264, s2 = s - r * 264;
        int sx = s2 >> 2;
        int g = (s2 & 3) ^ swz(sx);
        int yy = y + r - 1, xx = x0 + sx - 1;
        bool ok = (s < SLOTS) && ((unsigned)yy < 128u) && ((unsigned)xx < 128u);
        sptr[it] = ok ? inImg + ((size_t)yy * 128 + xx) * CIN + g * 8
                      : (const bf16*)(zpage + (tid & 255) * 16);
    }
    auto stage = [&](int kc, int buf) {
#pragma unroll
        for (int it = 0; it < 4; ++it) {
            if (it * 256 + tid < SLOTS)
                gll16(sptr[it] + kc * 32, &smem[buf][it * 2048 + wave * 512]);
        }
    };

    f32x4 acc = f32x4{0.f, 0.f, 0.f, 0.f};

    stage(0, 0);
    for (int kc = 0; kc < KC; ++kc) {
        __syncthreads();
        if (kc + 1 < KC) stage(kc + 1, (kc + 1) & 1);
        const short* sb = smem[kc & 1];
#pragma unroll
        for (int ky = 0; ky < 3; ++ky) {
#pragma unroll
            for (int kx = 0; kx < 3; ++kx) {
                bf16x8 aF = *(const bf16x8*)(const void*)(wT +
                    ((((size_t)(ky * 3 + kx) * KC + kc) * 4 + q) * COUT + n16) * 8);
                int xt = wave * 16 + n16 + kx;
                int slot = xt * 4 + (q ^ swz(xt));
                bf16x8 bF = *(const bf16x8*)(const void*)&sb[ky * 2112 + slot * 8];
                acc = __builtin_amdgcn_mfma_f32_16x16x32_bf16(aF, bF, acc, 0, 0, 0);
            }
        }
    }

    // bias + relu; online partials over this 64px half-row (co = q*4+r)
    float v[4];
    int x = x0 + wave * 16 + n16;
    float px = -1.f + (2.f / 127.f) * x;
#pragma unroll
    for (int r = 0; r < 4; ++r) {
        float t = acc[r] + bias[q * 4 + r];
        v[r] = t > 0.f ? t : 0.f;
    }
    float M[4];
#pragma unroll
    for (int r = 0; r < 4; ++r) {
        M[r] = v[r];
        M[r] = fmaxf(M[r], __shfl_xor(M[r], 1));
        M[r] = fmaxf(M[r], __shfl_xor(M[r], 2));
        M[r] = fmaxf(M[r], __shfl_xor(M[r], 4));
        M[r] = fmaxf(M[r], __shfl_xor(M[r], 8));
    }
    if (n16 == 0)
#pragma unroll
        for (int r = 0; r < 4; ++r) sred[0][wave][q * 4 + r] = M[r];
    __syncthreads();
#pragma unroll
    for (int r = 0; r < 4; ++r) {
        M[r] = fmaxf(fmaxf(sred[0][0][q * 4 + r], sred[0][1][q * 4 + r]),
                     fmaxf(sred[0][2][q * 4 + r], sred[0][3][q * 4 + r]));
    }
    float s[4], sx[4];
#pragma unroll
    for (int r = 0; r < 4; ++r) {
        float e = expf(v[r] - M[r]);
        s[r] = e; sx[r] = e * px;
        s[r] += __shfl_xor(s[r], 1);  sx[r] += __shfl_xor(sx[r], 1);
        s[r] += __shfl_xor(s[r], 2);  sx[r] += __shfl_xor(sx[r], 2);
        s[r] += __shfl_xor(s[r], 4);  sx[r] += __shfl_xor(sx[r], 4);
        s[r] += __shfl_xor(s[r], 8);  sx[r] += __shfl_xor(sx[r], 8);
    }
    __syncthreads();
    if (n16 == 0)
#pragma unroll
        for (int r = 0; r < 4; ++r) {
            sred[1][wave][q * 4 + r] = s[r];
            sred[2][wave][q * 4 + r] = sx[r];
        }
    __syncthreads();
    if (tid < 16) {
        float S = sred[1][0][tid] + sred[1][1][tid] + sred[1][2][tid] + sred[1][3][tid];
        float SX = sred[2][0][tid] + sred[2][1][tid] + sred[2][2][tid] + sred[2][3][tid];
        float Mv = fmaxf(fmaxf(sred[0][0][tid], sred[0][1][tid]),
                         fmaxf(sred[0][2][tid], sred[0][3][tid]));
        float* pp = partial + (((size_t)gimg * 16 + tid) * 256 + (y * 2 + xh)) * 4;
        pp[0] = Mv; pp[1] = S; pp[2] = SX;
    }
}

// ---------------- persistent LSTM: merge + 16 diagonals, 1 dispatch ---------
__device__ inline float imgfeat(const float* featm, const float* feats,
                                int b, int t, int k)
{
    int idx = (b * 10 + t) * 32;
    return k < 32 ? featm[idx + k] : feats[idx + k - 32];
}

__global__ __launch_bounds__(256) void lstm_all_k(
    const bf16* __restrict__ wih0p, const bf16* __restrict__ whh0b,
    const bf16* __restrict__ wihrb, const bf16* __restrict__ whhrb,
    const float* __restrict__ bih0, const float* __restrict__ bhh0,
    const float* __restrict__ bihr, const float* __restrict__ bhhr,
    const float* __restrict__ states, const float* __restrict__ partial,
    float* __restrict__ featm, float* __restrict__ feats,
    float* hAll,
    const float* __restrict__ out_w, const float* __restrict__ out_b,
    float* __restrict__ out, unsigned* bar)
{
    const int bid = blockIdx.x;          // 0..895
    const int l = bid >> 7;              // 0..6
    const int jb = bid & 127;
    const int tid = threadIdx.x;
    __shared__ float xs[4 * 1088];
    unsigned tgt = 896;

    // ---- phase 0: softmax merge (blocks 0..79 = gimg) ----
    if (bid < 80) {
        const int img = bid;
        const int cam = img / 40, li = img % 40;
        float* feat = cam ? feats : featm;
        const int co = tid >> 4, s = tid & 15;
        const float* base = partial + ((size_t)img * 16 + co) * 256 * 4;
        float M = -1e30f, S = 0.f, SX = 0.f, SY = 0.f;
        for (int i = s; i < 256; i += 16) {
            float m = base[i * 4], sv = base[i * 4 + 1], sxv = base[i * 4 + 2];
            float py = -1.f + (2.f / 127.f) * (i >> 1);
            float Mn = fmaxf(M, m);
            float w0 = expf(M - Mn), w1 = expf(m - Mn);
            S = S * w0 + sv * w1;
            SX = SX * w0 + sxv * w1;
            SY = SY * w0 + sv * py * w1;
            M = Mn;
        }
#pragma unroll
        for (int mask = 1; mask < 16; mask <<= 1) {
            float Mo = __shfl_xor(M, mask), So = __shfl_xor(S, mask);
            float SXo = __shfl_xor(SX, mask), SYo = __shfl_xor(SY, mask);
            float Mn = fmaxf(M, Mo);
            float w0 = expf(M - Mn), w1 = expf(Mo - Mn);
            S = S * w0 + So * w1; SX = SX * w0 + SXo * w1; SY = SY * w0 + SYo * w1;
            M = Mn;
        }
        if (s == 0) {
            feat[(size_t)li * 32 + 2 * co] = SX / S;
            feat[(size_t)li * 32 + 2 * co + 1] = SY / S;
        }
    }
    gridbar(bar, tgt); tgt += 896;

    // per-thread carried c state: thread (b, jloc, sub==0) owns c[b][jb*4+jloc]
    float creg = 0.f;

    const bf16 *wih = nullptr, *whh = nullptr;
    const float *bih = nullptr, *bhh = nullptr;
    int K1 = 72;
    if (l < 6) {
        if (l == 0) { wih = wih0p; whh = whh0b; bih = bih0; bhh = bhh0; K1 = 72; }
        else {
            wih = wihrb + (size_t)(l - 1) * 2048 * 576;
            whh = whhrb + (size_t)(l - 1) * 2048 * 512;
            bih = bihr + (l - 1) * 2048;
            bhh = bhhr + (l - 1) * 2048;
            K1 = 576;
        }
    }

    for (int d = 0; d < 16; ++d) {
        if (l == 6) {
            int t = d - 6;
            if (t >= 0 && t < 10 && jb == 0) {
                const float* h5 = hAll + ((size_t)(t + 1) * 6 + 5) * 2048;
                int p = tid >> 3, sub = tid & 7;
                if (p < 24) {
                    int b = p / 6, a = p % 6;
                    const float* wr = out_w + a * 576;
                    float acc = 0.f;
                    for (int k = sub; k < 512; k += 8) acc += wr[k] * h5[b * 512 + k];
                    for (int k = sub; k < 64; k += 8)
                        acc += wr[512 + k] * imgfeat(featm, feats, b, t, k);
                    acc += __shfl_xor(acc, 1);
                    acc += __shfl_xor(acc, 2);
                    acc += __shfl_xor(acc, 4);
                    if (sub == 0) out[(b * 10 + t) * 6 + a] = acc + out_b[a];
                }
            }
        } else {
            int t = d - l;
            if (t >= 0 && t < 10) {
                const float* hprev = (l == 0) ? nullptr
                                  : hAll + ((size_t)(t + 1) * 6 + (l - 1)) * 2048;
                const float* hold = hAll + ((size_t)t * 6 + l) * 2048;
                float* hnew = hAll + ((size_t)(t + 1) * 6 + l) * 2048;
                const int XS = K1 + 512;
                for (int i = tid; i < 4 * XS; i += 256) {
                    int b = i / XS, k = i - b * XS;
                    float v;
                    if (k < K1) {
                        if (hprev) v = (k < 512) ? hprev[b * 512 + k]
                                                 : imgfeat(featm, feats, b, t, k - 512);
                        else       v = (k < 6) ? states[(b * 10 + t) * 6 + k]
                                               : (k < 70 ? imgfeat(featm, feats, b, t, k - 6) : 0.f);
                    } else {
                        v = hold[b * 512 + (k - K1)];
                    }
                    xs[b * XS + k] = v;
                }
                __syncthreads();

                const int b = tid >> 6;
                const int jloc = (tid >> 4) & 3;
                const int sub = tid & 15;
                const int j = jb * 4 + jloc;
                const float* xb = xs + b * XS;
                const float* hp = xb + K1;
                float dg[4] = {0.f, 0.f, 0.f, 0.f};
                const int nb1 = K1 >> 3;
#pragma unroll
                for (int r = 0; r < 4; ++r) {
                    const uint4* w1 = reinterpret_cast<const uint4*>(wih + (size_t)(j + r * 512) * K1);
                    for (int g = sub; g < nb1; g += 16) {
                        uint4 u = w1[g]; const float* xp = xb + g * 8;
                        dg[r] += bflo(u.x) * xp[0] + bfhi(u.x) * xp[1]
                               + bflo(u.y) * xp[2] + bfhi(u.y) * xp[3]
                               + bflo(u.z) * xp[4] + bfhi(u.z) * xp[5]
                               + bflo(u.w) * xp[6] + bfhi(u.w) * xp[7];
                    }
                    const uint4* w2 = reinterpret_cast<const uint4*>(whh + (size_t)(j + r * 512) * 512);
                    for (int g = sub; g < 64; g += 16) {
                        uint4 u = w2[g]; const float* xp = hp + g * 8;
                        dg[r] += bflo(u.x) * xp[0] + bfhi(u.x) * xp[1]
                               + bflo(u.y) * xp[2] + bfhi(u.y) * xp[3]
                               + bflo(u.z) * xp[4] + bfhi(u.z) * xp[5]
                               + bflo(u.w) * xp[6] + bfhi(u.w) * xp[7];
                    }
                }
#pragma unroll
                for (int r = 0; r < 4; ++r) {
                    dg[r] += __shfl_xor(dg[r], 1);
                    dg[r] += __shfl_xor(dg[r], 2);
                    dg[r] += __shfl_xor(dg[r], 4);
                    dg[r] += __shfl_xor(dg[r], 8);
                }
                if (sub == 0) {
                    float gi = dg[0] + bih[j] + bhh[j];
                    float gf = dg[1] + bih[j + 512] + bhh[j + 512];
                    float gg = dg[2] + bih[j + 1024] + bhh[j + 1024];
                    float go = dg[3] + bih[j + 1536] + bhh[j + 1536];
                    float c2 = sigmoidf_(gf) * creg + sigmoidf_(gi) * tanhf(gg);
                    float h2 = sigmoidf_(go) * tanhf(c2);
                    creg = c2;
                    hnew[b * 512 + j] = h2;
                }
            }
        }
        if (d < 15) { gridbar(bar, tgt); tgt += 896; }
    }
}

// ---------------- host orchestration ----------------------------------------
extern "C" void kernel_launch(void* const* d_in, const int* in_sizes, int n_in,
                              void* d_out, int out_size, void* d_ws, size_t ws_size,
                              hipStream_t stream)
{
    const float* seq_m = (const float*)d_in[0];
    const float* seq_s = (const float*)d_in[1];
    const float* states = (const float*)d_in[2];
    const float *cw[2][4], *cb[2][4];
    for (int cam = 0; cam < 2; ++cam)
        for (int j = 0; j < 4; ++j) {
            cw[cam][j] = (const float*)d_in[3 + cam * 8 + j * 2];
            cb[cam][j] = (const float*)d_in[3 + cam * 8 + j * 2 + 1];
        }
    const float* wih0  = (const float*)d_in[19];
    const float* whh0  = (const float*)d_in[20];
    const float* bih0  = (const float*)d_in[21];
    const float* bhh0  = (const float*)d_in[22];
    const float* wih_r = (const float*)d_in[23];
    const float* whh_r = (const float*)d_in[24];
    const float* bih_r = (const float*)d_in[25];
    const float* bhh_r = (const float*)d_in[26];
    const float* out_w = (const float*)d_in[27];
    const float* out_b = (const float*)d_in[28];
    float* out = (float*)d_out;

    // ---- workspace carve (256B-aligned) ----
    char* wsc = (char*)d_ws;
    auto carve = [&](size_t bytes) {
        char* p = wsc;
        wsc += (bytes + 255) & ~(size_t)255;
        return p;
    };
    float* featm = (float*)carve(40 * 32 * 4);
    float* feats = (float*)carve(40 * 32 * 4);
    float* hAll  = (float*)carve((size_t)11 * 6 * 2048 * 4);
    char*  zpage = carve(8192);
    unsigned* bar = (unsigned*)carve(256);
    float* partial = (float*)carve((size_t)80 * 16 * 256 * 4 * 4);
    const int wtElts[4] = {3072, 18432, 73728, 18432};
    bf16* wT[2][4];
    for (int cam = 0; cam < 2; ++cam)
        for (int j = 0; j < 4; ++j) wT[cam][j] = (bf16*)carve(wtElts[j] * 2);
    bf16* wih0p = (bf16*)carve((size_t)2048 * 72 * 2);
    bf16* whh0b = (bf16*)carve((size_t)2048 * 512 * 2);
    bf16* wihrb = (bf16*)carve((size_t)5 * 2048 * 576 * 2);
    bf16* whhrb = (bf16*)carve((size_t)5 * 2048 * 512 * 2);

    size_t used = (size_t)(wsc - (char*)d_ws);
    size_t rem = ws_size > used ? ws_size - used : 0;
    int CHI = 1;
    const int cands[7] = {20, 10, 8, 5, 4, 2, 1};
    for (int i = 0; i < 7; ++i) {
        size_t need = (size_t)2 * cands[i] * (128 + 64) * HWPX * 2;
        if (need <= rem) { CHI = cands[i]; break; }
    }
    bf16* bufA = (bf16*)carve((size_t)2 * CHI * HWPX * 128 * 2);
    bf16* bufB = (bf16*)carve((size_t)2 * CHI * HWPX * 64 * 2);

    hipMemsetAsync(hAll, 0, 6 * 2048 * 4, stream);       // t=-1 slot
    hipMemsetAsync(zpage, 0, 8192 + 256, stream);        // zpage + bar (contiguous)

    // ---- weight preps ----
    prep_lstm_k<<<2048, 256, 0, stream>>>(wih0, whh0, wih_r, whh_r,
                                          wih0p, whh0b, wihrb, whhrb);
    ConvW cwArg;
    for (int cam = 0; cam < 2; ++cam)
        for (int j = 0; j < 4; ++j) {
            cwArg.src[cam * 4 + j] = cw[cam][j];
            cwArg.dst[cam * 4 + j] = wT[cam][j];
        }
    prep_conv_k<<<888, 256, 0, stream>>>(cwArg);

    // ---- CNN + fused spatial softmax (both cams per dispatch) ----
    for (int c0 = 0; c0 < 40; c0 += CHI) {
        int ch = (40 - c0) < CHI ? (40 - c0) : CHI;
        conv0_nhwc<<<dim3(128, 2, ch), 256, 0, stream>>>(
            seq_m, seq_s, wT[0][0], wT[1][0], cb[0][0], cb[1][0], bufA, c0);
        conv2r<32, 64><<<dim3(128, 2, ch), 256, 0, stream>>>(
            bufA, wT[0][1], wT[1][1], cb[0][1], cb[1][1], bufB, zpage);
        conv2r<64, 128><<<dim3(128, 2, ch), 256, 0, stream>>>(
            bufB, wT[0][2], wT[1][2], cb[0][2], cb[1][2], bufA, zpage);
        conv4_xs<<<dim3(256, 2, ch), 256, 0, stream>>>(
            bufA, wT[0][3], wT[1][3], cb[0][3], cb[1][3], partial, zpage, c0);
    }

    // ---- persistent LSTM: merge + 16 diagonals + projections, 1 dispatch ---
    lstm_all_k<<<896, 256, 0, stream>>>(
        wih0p, whh0b, wihrb, whhrb, bih0, bhh0, bih_r, bhh_r,
        states, partial, featm, feats, hAll, out_w, out_b, out, bar);
}

// Round 9
// 1136.206 us; speedup vs baseline: 4.3971x; 4.3971x over previous
//
#include <hip/hip_runtime.h>
#include <hip/hip_bf16.h>
#include <math.h>

typedef __hip_bfloat16 bf16;
typedef short bf16x8 __attribute__((ext_vector_type(8)));
typedef float f32x4 __attribute__((ext_vector_type(4)));

static constexpr int HWPX = 16384;   // 128*128

__device__ inline float sigmoidf_(float x) { return 1.0f / (1.0f + expf(-x)); }
__device__ inline float bflo(unsigned u) { return __uint_as_float(u << 16); }
__device__ inline float bfhi(unsigned u) { return __uint_as_float(u & 0xffff0000u); }
__device__ inline int swz(int x) { return (x ^ (x >> 2)) & 3; }

// async global->LDS, 16B per lane; lds base wave-uniform (lane i -> +i*16)
__device__ inline void gll16(const bf16* g, short* l) {
    __builtin_amdgcn_global_load_lds(
        (const __attribute__((address_space(1))) void*)g,
        (__attribute__((address_space(3))) void*)l, 16, 0, 0);
}

// ---------------- prep: LSTM weights -> bf16 (wih0 padded 70->72) -----------
__global__ __launch_bounds__(256) void prep_lstm_k(
    const float* __restrict__ wih0, const float* __restrict__ whh0,
    const float* __restrict__ wihr, const float* __restrict__ whhr,
    bf16* __restrict__ d0, bf16* __restrict__ d1,
    bf16* __restrict__ d2, bf16* __restrict__ d3)
{
    const size_t nA = 2048ull * 72, nB = 2048ull * 512;
    const size_t nC = 5ull * 2048 * 576, nD = 5ull * 2048 * 512;
    for (size_t i = blockIdx.x * 256ull + threadIdx.x; i < nA + nB + nC + nD;
         i += (size_t)gridDim.x * 256) {
        if (i < nA) {
            int c = (int)(i % 72), r = (int)(i / 72);
            d0[i] = __float2bfloat16(c < 70 ? wih0[(size_t)r * 70 + c] : 0.f);
        } else if (i < nA + nB) {
            size_t k = i - nA; d1[k] = __float2bfloat16(whh0[k]);
        } else if (i < nA + nB + nC) {
            size_t k = i - nA - nB; d2[k] = __float2bfloat16(wihr[k]);
        } else {
            size_t k = i - nA - nB - nC; d3[k] = __float2bfloat16(whhr[k]);
        }
    }
}

// ---------------- prep: conv weights, both cams -----------------------------
struct ConvW {
    const float* src[8];
    bf16* dst[8];
};

__global__ __launch_bounds__(256) void prep_conv_k(ConvW a)
{
    const int sizes[4] = {3072, 18432, 73728, 18432};
    const int cins[4] = {3, 32, 64, 128};
    const int couts[4] = {32, 64, 128, 16};
    int total = 2 * 113664;
    for (int idx = blockIdx.x * 256 + threadIdx.x; idx < total; idx += gridDim.x * 256) {
        int i = idx, cam = 0;
        if (i >= 113664) { cam = 1; i -= 113664; }
        int layer = 0;
        while (layer < 3 && i >= sizes[layer]) { i -= sizes[layer]; ++layer; }
        const float* w = a.src[cam * 4 + layer];
        bf16* d = a.dst[cam * 4 + layer];
        if (layer == 0) {
            // [3ky][32co][32k], k = kx*8 + c
            int k = i & 31, co = (i >> 5) & 31, ky = i >> 10;
            int kx = k >> 3, c = k & 7;
            float v = (kx < 3 && c < 3) ? w[((co * 3 + c) * 3 + ky) * 3 + kx] : 0.f;
            d[i] = __float2bfloat16(v);
        } else {
            // dst [tap][kc][q][co][8]
            int CIN = cins[layer], COUT = couts[layer], KC = CIN / 32;
            int e = i & 7;
            int t2 = i >> 3;
            int co = t2 % COUT;
            int t3 = t2 / COUT;
            int q = t3 & 3;
            int t4 = t3 >> 2;
            int kc = t4 % KC;
            int tap = t4 / KC;
            d[i] = __float2bfloat16(w[((size_t)(co * CIN + kc * 32 + q * 8 + e)) * 9 + tap]);
        }
    }
}

// ---------------- conv L0: fp32 NCHW in, NHWC-32 out, cam-folded ------------
__global__ __launch_bounds__(256) void conv0_nhwc(
    const float* __restrict__ srcm, const float* __restrict__ srcs,
    const bf16* __restrict__ w0m, const bf16* __restrict__ w0s,
    const float* __restrict__ bm, const float* __restrict__ bs,
    bf16* __restrict__ out, int c0)
{
    const int y = blockIdx.x;
    const int cam = blockIdx.y;
    const int img = blockIdx.z;
    const int ci_ = cam * gridDim.z + img;
    const float* inImg = (cam ? srcs : srcm) + (size_t)(c0 + img) * 3 * HWPX;
    const bf16* wT0 = cam ? w0s : w0m;
    const float* bias = cam ? bs : bm;
    const int tid = threadIdx.x;
    const int wave = tid >> 6, lane = tid & 63;
    const int wm = wave & 1, wn = wave >> 1;
    const int q = lane >> 4, n16 = lane & 15;

    __shared__ short smem[3 * 130 * 16];

    for (int d = tid; d < 3 * 130; d += 256) {
        int x = d % 130, r = d / 130;
        int yy = y + r - 1, xx = x - 1;
        bf16 v8[8];
#pragma unroll
        for (int c = 0; c < 8; ++c) v8[c] = __float2bfloat16(0.f);
        if ((unsigned)yy < 128u && (unsigned)xx < 128u) {
            int o = yy * 128 + xx;
            v8[0] = __float2bfloat16(inImg[o]);
            v8[1] = __float2bfloat16(inImg[HWPX + o]);
            v8[2] = __float2bfloat16(inImg[2 * HWPX + o]);
        }
        *(bf16x8*)(void*)&smem[(r * 130 + x) * 16] = *(bf16x8*)(void*)v8;
        *(bf16x8*)(void*)&smem[(r * 130 + x) * 16 + 8] = (bf16x8)0;
    }
    __syncthreads();

    f32x4 acc[4];
#pragma unroll
    for (int nt = 0; nt < 4; ++nt) acc[nt] = f32x4{0.f, 0.f, 0.f, 0.f};

    const int co = wm * 16 + n16;
#pragma unroll
    for (int ky = 0; ky < 3; ++ky) {
        bf16x8 aF = *(const bf16x8*)(const void*)(wT0 + ((size_t)(ky * 32 + co) * 32) + q * 8);
#pragma unroll
        for (int nt = 0; nt < 4; ++nt) {
            int x = (wn * 4 + nt) * 16 + n16;
            int off = (q < 3) ? (ky * 130 + x + q) * 16 : (ky * 130 + x) * 16 + 8;
            bf16x8 bF = *(const bf16x8*)(const void*)&smem[off];
            acc[nt] = __builtin_amdgcn_mfma_f32_16x16x32_bf16(aF, bF, acc[nt], 0, 0, 0);
        }
    }

    int co0 = wm * 16 + q * 4;
#pragma unroll
    for (int nt = 0; nt < 4; ++nt) {
        int x = (wn * 4 + nt) * 16 + n16;
        bf16 tmp[4];
#pragma unroll
        for (int r = 0; r < 4; ++r) {
            float v = acc[nt][r] + bias[co0 + r];
            tmp[r] = __float2bfloat16(v > 0.f ? v : 0.f);
        }
        *reinterpret_cast<uint2*>(out + ((size_t)ci_ * HWPX + y * 128 + x) * 32 + co0)
            = *reinterpret_cast<uint2*>(tmp);
    }
}

// ---------------- mid convs: 2 rows x 64px per block, gll dbuf --------------
template <int CIN, int COUT>
__global__ __launch_bounds__(256, 4) void conv2r(
    const bf16* __restrict__ in, const bf16* __restrict__ wTm,
    const bf16* __restrict__ wTs, const float* __restrict__ bm,
    const float* __restrict__ bs, bf16* __restrict__ out,
    const char* __restrict__ zpage)
{
    constexpr int KC = CIN / 32;
    constexpr int NB = (KC > 1) ? 2 : 1;
    constexpr int MW = COUT / 32;       // co tiles per wave (2 co-halves)
    constexpr int SLOTS = 4 * 264;      // 4 rows x 66 x x 4 granules

    const int y0 = (blockIdx.x >> 1) * 2;
    const int x0 = (blockIdx.x & 1) * 64;
    const int cam = blockIdx.y;
    const int img = blockIdx.z;
    const int ci_ = cam * gridDim.z + img;
    const bf16* wT = cam ? wTs : wTm;
    const float* bias = cam ? bs : bm;
    const int tid = threadIdx.x;
    const int wave = tid >> 6, lane = tid & 63;
    const int wrow = wave >> 1, wm = wave & 1;
    const int q = lane >> 4, n16 = lane & 15;

    __shared__ short smem[NB][SLOTS * 8];
    const bf16* inImg = in + (size_t)ci_ * HWPX * CIN;

    const bf16* sptr[5];
#pragma unroll
    for (int it = 0; it < 5; ++it) {
        int s = it * 256 + tid;
        int r = s / 264, s2 = s - r * 264;
        int sx = s2 >> 2;
        int g = (s2 & 3) ^ swz(sx);
        int yy = y0 + r - 1, xx = x0 + sx - 1;
        bool ok = (s < SLOTS) && ((unsigned)yy < 128u) && ((unsigned)xx < 128u);
        sptr[it] = ok ? inImg + ((size_t)yy * 128 + xx) * CIN + g * 8
                      : (const bf16*)(zpage + (tid & 255) * 16);
    }
    auto stage = [&](int kc, int buf) {
#pragma unroll
        for (int it = 0; it < 5; ++it) {
            if (it * 256 + tid < SLOTS)
                gll16(sptr[it] + kc * 32, &smem[buf][it * 2048 + wave * 512]);
        }
    };

    f32x4 acc[MW][4];
#pragma unroll
    for (int mt = 0; mt < MW; ++mt)
#pragma unroll
        for (int nt = 0; nt < 4; ++nt) acc[mt][nt] = f32x4{0.f, 0.f, 0.f, 0.f};

    stage(0, 0);
    for (int kc = 0; kc < KC; ++kc) {
        __syncthreads();
        if (kc + 1 < KC) stage(kc + 1, (kc + 1) % NB);
        const short* sb = smem[kc % NB];
#pragma unroll
        for (int ky = 0; ky < 3; ++ky) {
#pragma unroll
            for (int kx = 0; kx < 3; ++kx) {
                bf16x8 aF[MW];
#pragma unroll
                for (int mt = 0; mt < MW; ++mt) {
                    int co = (wm * MW + mt) * 16 + n16;
                    aF[mt] = *(const bf16x8*)(const void*)(wT +
                        ((((size_t)(ky * 3 + kx) * KC + kc) * 4 + q) * COUT + co) * 8);
                }
#pragma unroll
                for (int nt = 0; nt < 4; ++nt) {
                    int xt = nt * 16 + n16 + kx;           // 0..65
                    int slot = (wrow + ky) * 264 + xt * 4 + (q ^ swz(xt));
                    bf16x8 bF = *(const bf16x8*)(const void*)&sb[slot * 8];
#pragma unroll
                    for (int mt = 0; mt < MW; ++mt)
                        acc[mt][nt] = __builtin_amdgcn_mfma_f32_16x16x32_bf16(
                            aF[mt], bF, acc[mt][nt], 0, 0, 0);
                }
            }
        }
    }

    const int y = y0 + wrow;
#pragma unroll
    for (int mt = 0; mt < MW; ++mt) {
        int co0 = (wm * MW + mt) * 16 + q * 4;
#pragma unroll
        for (int nt = 0; nt < 4; ++nt) {
            int x = x0 + nt * 16 + n16;
            bf16 tmp[4];
#pragma unroll
            for (int r = 0; r < 4; ++r) {
                float v = acc[mt][nt][r] + bias[co0 + r];
                tmp[r] = __float2bfloat16(v > 0.f ? v : 0.f);
            }
            *reinterpret_cast<uint2*>(out + ((size_t)ci_ * HWPX + y * 128 + x) * COUT + co0)
                = *reinterpret_cast<uint2*>(tmp);
        }
    }
}

// ---------------- conv4 (128->16): half-row x-split + softmax partials ------
__global__ __launch_bounds__(256, 6) void conv4_xs(
    const bf16* __restrict__ in, const bf16* __restrict__ wTm,
    const bf16* __restrict__ wTs, const float* __restrict__ bm,
    const float* __restrict__ bs,
    float* __restrict__ partial,   // [gimg][16][256] x {M,S,SX,-}
    const char* __restrict__ zpage, int c0)
{
    constexpr int CIN = 128, COUT = 16, KC = 4;
    constexpr int SLOTS = 3 * 66 * 4;
    const int y = blockIdx.x >> 1;
    const int xh = blockIdx.x & 1;
    const int x0 = xh * 64;
    const int cam = blockIdx.y;
    const int img = blockIdx.z;
    const int ci_ = cam * gridDim.z + img;
    const int gimg = cam * 40 + c0 + img;
    const bf16* wT = cam ? wTs : wTm;
    const float* bias = cam ? bs : bm;
    const int tid = threadIdx.x;
    const int wave = tid >> 6, lane = tid & 63;
    const int q = lane >> 4, n16 = lane & 15;

    __shared__ short smem[2][SLOTS * 8];
    __shared__ float sred[3][4][16];
    const bf16* inImg = in + (size_t)ci_ * HWPX * CIN;

    const bf16* sptr[4];
#pragma unroll
    for (int it = 0; it < 4; ++it) {
        int s = it * 256 + tid;
        int r = s / 264, s2 = s - r * 264;
        int sx = s2 >> 2;
        int g = (s2 & 3) ^ swz(sx);
        int yy = y + r - 1, xx = x0 + sx - 1;
        bool ok = (s < SLOTS) && ((unsigned)yy < 128u) && ((unsigned)xx < 128u);
        sptr[it] = ok ? inImg + ((size_t)yy * 128 + xx) * CIN + g * 8
                      : (const bf16*)(zpage + (tid & 255) * 16);
    }
    auto stage = [&](int kc, int buf) {
#pragma unroll
        for (int it = 0; it < 4; ++it) {
            if (it * 256 + tid < SLOTS)
                gll16(sptr[it] + kc * 32, &smem[buf][it * 2048 + wave * 512]);
        }
    };

    f32x4 acc = f32x4{0.f, 0.f, 0.f, 0.f};

    stage(0, 0);
    for (int kc = 0; kc < KC; ++kc) {
        __syncthreads();
        if (kc + 1 < KC) stage(kc + 1, (kc + 1) & 1);
        const short* sb = smem[kc & 1];
#pragma unroll
        for (int ky = 0; ky < 3; ++ky) {
#pragma unroll
            for (int kx = 0; kx < 3; ++kx) {
                bf16x8 aF = *(const bf16x8*)(const void*)(wT +
                    ((((size_t)(ky * 3 + kx) * KC + kc) * 4 + q) * COUT + n16) * 8);
                int xt = wave * 16 + n16 + kx;
                int slot = xt * 4 + (q ^ swz(xt));
                bf16x8 bF = *(const bf16x8*)(const void*)&sb[ky * 2112 + slot * 8];
                acc = __builtin_amdgcn_mfma_f32_16x16x32_bf16(aF, bF, acc, 0, 0, 0);
            }
        }
    }

    // bias + relu; online partials over this 64px half-row (co = q*4+r)
    float v[4];
    int x = x0 + wave * 16 + n16;
    float px = -1.f + (2.f / 127.f) * x;
#pragma unroll
    for (int r = 0; r < 4; ++r) {
        float t = acc[r] + bias[q * 4 + r];
        v[r] = t > 0.f ? t : 0.f;
    }
    float M[4];
#pragma unroll
    for (int r = 0; r < 4; ++r) {
        M[r] = v[r];
        M[r] = fmaxf(M[r], __shfl_xor(M[r], 1));
        M[r] = fmaxf(M[r], __shfl_xor(M[r], 2));
        M[r] = fmaxf(M[r], __shfl_xor(M[r], 4));
        M[r] = fmaxf(M[r], __shfl_xor(M[r], 8));
    }
    if (n16 == 0)
#pragma unroll
        for (int r = 0; r < 4; ++r) sred[0][wave][q * 4 + r] = M[r];
    __syncthreads();
#pragma unroll
    for (int r = 0; r < 4; ++r) {
        M[r] = fmaxf(fmaxf(sred[0][0][q * 4 + r], sred[0][1][q * 4 + r]),
                     fmaxf(sred[0][2][q * 4 + r], sred[0][3][q * 4 + r]));
    }
    float s[4], sx[4];
#pragma unroll
    for (int r = 0; r < 4; ++r) {
        float e = expf(v[r] - M[r]);
        s[r] = e; sx[r] = e * px;
        s[r] += __shfl_xor(s[r], 1);  sx[r] += __shfl_xor(sx[r], 1);
        s[r] += __shfl_xor(s[r], 2);  sx[r] += __shfl_xor(sx[r], 2);
        s[r] += __shfl_xor(s[r], 4);  sx[r] += __shfl_xor(sx[r], 4);
        s[r] += __shfl_xor(s[r], 8);  sx[r] += __shfl_xor(sx[r], 8);
    }
    __syncthreads();
    if (n16 == 0)
#pragma unroll
        for (int r = 0; r < 4; ++r) {
            sred[1][wave][q * 4 + r] = s[r];
            sred[2][wave][q * 4 + r] = sx[r];
        }
    __syncthreads();
    if (tid < 16) {
        float S = sred[1][0][tid] + sred[1][1][tid] + sred[1][2][tid] + sred[1][3][tid];
        float SX = sred[2][0][tid] + sred[2][1][tid] + sred[2][2][tid] + sred[2][3][tid];
        float Mv = fmaxf(fmaxf(sred[0][0][tid], sred[0][1][tid]),
                         fmaxf(sred[0][2][tid], sred[0][3][tid]));
        float* pp = partial + (((size_t)gimg * 16 + tid) * 256 + (y * 2 + xh)) * 4;
        pp[0] = Mv; pp[1] = S; pp[2] = SX;
    }
}

// ---------------- merge partials -> (ex, ey), both cams ---------------------
__global__ __launch_bounds__(256) void ssmerge_k(
    const float* __restrict__ partial, float* __restrict__ featm,
    float* __restrict__ feats)
{
    const int img = blockIdx.x;          // 0..79
    const int cam = img / 40, li = img % 40;
    float* feat = cam ? feats : featm;
    const int tid = threadIdx.x;
    const int co = tid >> 4, s = tid & 15;
    const float* base = partial + ((size_t)img * 16 + co) * 256 * 4;
    float M = -1e30f, S = 0.f, SX = 0.f, SY = 0.f;
    for (int i = s; i < 256; i += 16) {
        float m = base[i * 4], sv = base[i * 4 + 1], sxv = base[i * 4 + 2];
        float py = -1.f + (2.f / 127.f) * (i >> 1);
        float Mn = fmaxf(M, m);
        float w0 = expf(M - Mn), w1 = expf(m - Mn);
        S = S * w0 + sv * w1;
        SX = SX * w0 + sxv * w1;
        SY = SY * w0 + sv * py * w1;
        M = Mn;
    }
#pragma unroll
    for (int mask = 1; mask < 16; mask <<= 1) {
        float Mo = __shfl_xor(M, mask), So = __shfl_xor(S, mask);
        float SXo = __shfl_xor(SX, mask), SYo = __shfl_xor(SY, mask);
        float Mn = fmaxf(M, Mo);
        float w0 = expf(M - Mn), w1 = expf(Mo - Mn);
        S = S * w0 + So * w1; SX = SX * w0 + SXo * w1; SY = SY * w0 + SYo * w1;
        M = Mn;
    }
    if (s == 0) {
        feat[(size_t)li * 32 + 2 * co] = SX / S;
        feat[(size_t)li * 32 + 2 * co + 1] = SY / S;
    }
}

// ---------------- LSTM: anti-diagonal wavefront (R7-proven) -----------------
__device__ inline float imgfeat(const float* featm, const float* feats,
                                int b, int t, int k)
{
    int idx = (b * 10 + t) * 32;
    return k < 32 ? featm[idx + k] : feats[idx + k - 32];
}

__global__ __launch_bounds__(256) void lstm_diag_k(
    const bf16* __restrict__ wih0p, const bf16* __restrict__ whh0b,
    const bf16* __restrict__ wihrb, const bf16* __restrict__ whhrb,
    const float* __restrict__ bih0, const float* __restrict__ bhh0,
    const float* __restrict__ bihr, const float* __restrict__ bhhr,
    const float* __restrict__ states,
    const float* __restrict__ featm, const float* __restrict__ feats,
    float* __restrict__ hAll, float* __restrict__ cAll,
    const float* __restrict__ out_w, const float* __restrict__ out_b,
    float* __restrict__ out, int d)
{
    const int l = blockIdx.y;
    const int tid = threadIdx.x;

    if (l == 6) {   // out projection for t = d-6
        int t = d - 6;
        if (t < 0 || t >= 10 || blockIdx.x != 0) return;
        const float* h5 = hAll + ((size_t)(t + 1) * 6 + 5) * 2048;
        int p = tid >> 3, sub = tid & 7;
        if (p >= 24) return;
        int b = p / 6, a = p % 6;
        const float* wr = out_w + a * 576;
        float acc = 0.f;
        for (int k = sub; k < 512; k += 8) acc += wr[k] * h5[b * 512 + k];
        for (int k = sub; k < 64; k += 8) acc += wr[512 + k] * imgfeat(featm, feats, b, t, k);
        acc += __shfl_xor(acc, 1);
        acc += __shfl_xor(acc, 2);
        acc += __shfl_xor(acc, 4);
        if (sub == 0) out[(b * 10 + t) * 6 + a] = acc + out_b[a];
        return;
    }

    const int t = d - l;
    if (t < 0 || t >= 10) return;

    const bf16 *wih, *whh;
    const float *bih, *bhh;
    int K1;
    if (l == 0) { wih = wih0p; whh = whh0b; bih = bih0; bhh = bhh0; K1 = 72; }
    else {
        wih = wihrb + (size_t)(l - 1) * 2048 * 576;
        whh = whhrb + (size_t)(l - 1) * 2048 * 512;
        bih = bihr + (l - 1) * 2048;
        bhh = bhhr + (l - 1) * 2048;
        K1 = 576;
    }
    const float* hprev = (l == 0) ? nullptr : hAll + ((size_t)(t + 1) * 6 + (l - 1)) * 2048;
    const float* hold  = hAll + ((size_t)t * 6 + l) * 2048;
    float* hnew        = hAll + ((size_t)(t + 1) * 6 + l) * 2048;
    float* cst         = cAll + (size_t)l * 2048;

    const int XS = K1 + 512;
    __shared__ float xs[4 * 1088];
    for (int i = tid; i < 4 * XS; i += 256) {
        int b = i / XS, k = i - b * XS;
        float v;
        if (k < K1) {
            if (hprev) v = (k < 512) ? hprev[b * 512 + k]
                                     : imgfeat(featm, feats, b, t, k - 512);
            else       v = (k < 6) ? states[(b * 10 + t) * 6 + k]
                                   : (k < 70 ? imgfeat(featm, feats, b, t, k - 6) : 0.f);
        } else {
            v = hold[b * 512 + (k - K1)];
        }
        xs[b * XS + k] = v;
    }
    __syncthreads();

    const int b = tid >> 6;
    const int jloc = (tid >> 4) & 3;
    const int sub = tid & 15;
    const int j = blockIdx.x * 4 + jloc;
    const float* xb = xs + b * XS;
    const float* hp = xb + K1;
    float dg[4] = {0.f, 0.f, 0.f, 0.f};
    const int nb1 = K1 >> 3;
#pragma unroll
    for (int r = 0; r < 4; ++r) {
        const uint4* w1 = reinterpret_cast<const uint4*>(wih + (size_t)(j + r * 512) * K1);
        for (int g = sub; g < nb1; g += 16) {
            uint4 u = w1[g]; const float* xp = xb + g * 8;
            dg[r] += bflo(u.x) * xp[0] + bfhi(u.x) * xp[1] + bflo(u.y) * xp[2] + bfhi(u.y) * xp[3]
                   + bflo(u.z) * xp[4] + bfhi(u.z) * xp[5] + bflo(u.w) * xp[6] + bfhi(u.w) * xp[7];
        }
        const uint4* w2 = reinterpret_cast<const uint4*>(whh + (size_t)(j + r * 512) * 512);
        for (int g = sub; g < 64; g += 16) {
            uint4 u = w2[g]; const float* xp = hp + g * 8;
            dg[r] += bflo(u.x) * xp[0] + bfhi(u.x) * xp[1] + bflo(u.y) * xp[2] + bfhi(u.y) * xp[3]
                   + bflo(u.z) * xp[4] + bfhi(u.z) * xp[5] + bflo(u.w) * xp[6] + bfhi(u.w) * xp[7];
        }
    }
#pragma unroll
    for (int r = 0; r < 4; ++r) {
        dg[r] += __shfl_xor(dg[r], 1);
        dg[r] += __shfl_xor(dg[r], 2);
        dg[r] += __shfl_xor(dg[r], 4);
        dg[r] += __shfl_xor(dg[r], 8);
    }
    if (sub == 0) {
        float gi = dg[0] + bih[j] + bhh[j];
        float gf = dg[1] + bih[j + 512] + bhh[j + 512];
        float gg = dg[2] + bih[j + 1024] + bhh[j + 1024];
        float go = dg[3] + bih[j + 1536] + bhh[j + 1536];
        float cp = cst[b * 512 + j];
        float c2 = sigmoidf_(gf) * cp + sigmoidf_(gi) * tanhf(gg);
        float h2 = sigmoidf_(go) * tanhf(c2);
        cst[b * 512 + j] = c2;
        hnew[b * 512 + j] = h2;
    }
}

// ---------------- host orchestration ----------------------------------------
extern "C" void kernel_launch(void* const* d_in, const int* in_sizes, int n_in,
                              void* d_out, int out_size, void* d_ws, size_t ws_size,
                              hipStream_t stream)
{
    const float* seq_m = (const float*)d_in[0];
    const float* seq_s = (const float*)d_in[1];
    const float* states = (const float*)d_in[2];
    const float *cw[2][4], *cb[2][4];
    for (int cam = 0; cam < 2; ++cam)
        for (int j = 0; j < 4; ++j) {
            cw[cam][j] = (const float*)d_in[3 + cam * 8 + j * 2];
            cb[cam][j] = (const float*)d_in[3 + cam * 8 + j * 2 + 1];
        }
    const float* wih0  = (const float*)d_in[19];
    const float* whh0  = (const float*)d_in[20];
    const float* bih0  = (const float*)d_in[21];
    const float* bhh0  = (const float*)d_in[22];
    const float* wih_r = (const float*)d_in[23];
    const float* whh_r = (const float*)d_in[24];
    const float* bih_r = (const float*)d_in[25];
    const float* bhh_r = (const float*)d_in[26];
    const float* out_w = (const float*)d_in[27];
    const float* out_b = (const float*)d_in[28];
    float* out = (float*)d_out;

    // ---- workspace carve (256B-aligned) ----
    char* wsc = (char*)d_ws;
    auto carve = [&](size_t bytes) {
        char* p = wsc;
        wsc += (bytes + 255) & ~(size_t)255;
        return p;
    };
    float* featm = (float*)carve(40 * 32 * 4);
    float* feats = (float*)carve(40 * 32 * 4);
    float* hAll  = (float*)carve((size_t)11 * 6 * 2048 * 4);
    float* cAll  = (float*)carve((size_t)6 * 2048 * 4);
    char*  zpage = carve(8192);
    float* partial = (float*)carve((size_t)80 * 16 * 256 * 4 * 4);
    const int wtElts[4] = {3072, 18432, 73728, 18432};
    bf16* wT[2][4];
    for (int cam = 0; cam < 2; ++cam)
        for (int j = 0; j < 4; ++j) wT[cam][j] = (bf16*)carve(wtElts[j] * 2);
    bf16* wih0p = (bf16*)carve((size_t)2048 * 72 * 2);
    bf16* whh0b = (bf16*)carve((size_t)2048 * 512 * 2);
    bf16* wihrb = (bf16*)carve((size_t)5 * 2048 * 576 * 2);
    bf16* whhrb = (bf16*)carve((size_t)5 * 2048 * 512 * 2);

    size_t used = (size_t)(wsc - (char*)d_ws);
    size_t rem = ws_size > used ? ws_size - used : 0;
    int CHI = 1;
    const int cands[7] = {20, 10, 8, 5, 4, 2, 1};
    for (int i = 0; i < 7; ++i) {
        size_t need = (size_t)2 * cands[i] * (128 + 64) * HWPX * 2;
        if (need <= rem) { CHI = cands[i]; break; }
    }
    bf16* bufA = (bf16*)carve((size_t)2 * CHI * HWPX * 128 * 2);
    bf16* bufB = (bf16*)carve((size_t)2 * CHI * HWPX * 64 * 2);

    hipMemsetAsync(hAll, 0, 6 * 2048 * 4, stream);       // t=-1 slot
    hipMemsetAsync(cAll, 0, 6 * 2048 * 4, stream);
    hipMemsetAsync(zpage, 0, 8192, stream);

    // ---- weight preps ----
    prep_lstm_k<<<2048, 256, 0, stream>>>(wih0, whh0, wih_r, whh_r,
                                          wih0p, whh0b, wihrb, whhrb);
    ConvW cwArg;
    for (int cam = 0; cam < 2; ++cam)
        for (int j = 0; j < 4; ++j) {
            cwArg.src[cam * 4 + j] = cw[cam][j];
            cwArg.dst[cam * 4 + j] = wT[cam][j];
        }
    prep_conv_k<<<888, 256, 0, stream>>>(cwArg);

    // ---- CNN + fused spatial softmax (both cams per dispatch) ----
    for (int c0 = 0; c0 < 40; c0 += CHI) {
        int ch = (40 - c0) < CHI ? (40 - c0) : CHI;
        conv0_nhwc<<<dim3(128, 2, ch), 256, 0, stream>>>(
            seq_m, seq_s, wT[0][0], wT[1][0], cb[0][0], cb[1][0], bufA, c0);
        conv2r<32, 64><<<dim3(128, 2, ch), 256, 0, stream>>>(
            bufA, wT[0][1], wT[1][1], cb[0][1], cb[1][1], bufB, zpage);
        conv2r<64, 128><<<dim3(128, 2, ch), 256, 0, stream>>>(
            bufB, wT[0][2], wT[1][2], cb[0][2], cb[1][2], bufA, zpage);
        conv4_xs<<<dim3(256, 2, ch), 256, 0, stream>>>(
            bufA, wT[0][3], wT[1][3], cb[0][3], cb[1][3], partial, zpage, c0);
    }
    ssmerge_k<<<80, 256, 0, stream>>>(partial, featm, feats);

    // ---- LSTM wavefront: 16 diagonals cover 60 cells + 10 projections ------
    for (int d = 0; d < 16; ++d) {
        lstm_diag_k<<<dim3(128, 7), 256, 0, stream>>>(
            wih0p, whh0b, wihrb, whhrb, bih0, bhh0, bih_r, bhh_r,
            states, featm, feats, hAll, cAll, out_w, out_b, out, d);
    }
}